// Round 6
// baseline (151.941 us; speedup 1.0000x reference)
//
#include <hip/hip_runtime.h>

#define HW  16384
#define WD  128

__device__ __forceinline__ float ftanh(float v) {
    const float e = __expf(2.0f * v);
    return 1.0f - __fdividef(2.0f, e + 1.0f);
}

// ---- la_pre: conv1+bn1+tanh+conv2+bn2 -> nb (ch<8) / mask planes.
//   z = p*2 + h: half h computes conv2 rows h*5..h*5+4 (conv1 recomputed
//   per half: +256 FMA, buys 2x blocks -> 32 waves/CU for latency hiding).
//   NOTE: plain launch_bounds(256) — R4's (256,8) forced VGPR=32 and
//   spilled xv[32] to scratch (FETCH 157MB). Never bound min-waves here.
__global__ __launch_bounds__(256) void la_pre(
    const float* __restrict__ x,
    const float* __restrict__ w1, const float* __restrict__ b1,
    const float* __restrict__ g1, const float* __restrict__ be1,
    const float* __restrict__ m1, const float* __restrict__ v1,
    const float* __restrict__ w2, const float* __restrict__ b2,
    const float* __restrict__ g2, const float* __restrict__ be2,
    const float* __restrict__ m2, const float* __restrict__ v2,
    float* __restrict__ nb, float* __restrict__ mask)
{
    const int pix = blockIdx.x * blockDim.x + threadIdx.x;   // 0..16383
    const int b   = blockIdx.y;
    const int z   = blockIdx.z;                              // 0..15
    const int p   = z >> 1;                                  // t-group
    const int h   = z & 1;                                   // row half

    const float* xp = x + (size_t)(b * 256 + p * 32) * HW + pix;
    float xv[32];
#pragma unroll
    for (int c = 0; c < 32; ++c) xv[c] = xp[(size_t)c * HW];

    // conv1 + bn1 + tanh (weights/bn thread-uniform -> scalar loads)
    const float* w1g = w1 + p * 256;
    float tv[8];
#pragma unroll
    for (int o = 0; o < 8; ++o) {
        float a = 0.f;
#pragma unroll
        for (int ci = 0; ci < 32; ++ci) a = fmaf(xv[ci], w1g[o * 32 + ci], a);
        const int ch = p * 8 + o;
        const float inv = g1[ch] * rsqrtf(v1[ch] + 1e-5f);
        const float add = be1[ch] + (b1[ch] - m1[ch]) * inv;
        tv[o] = ftanh(fmaf(a, inv, add));
    }

    // conv2 rows h*5 .. h*5+4 of group p + bn2 -> nb (c<8) / mask (c>=8)
#pragma unroll
    for (int r = 0; r < 5; ++r) {
        const int o = h * 5 + r;
        const int c = p * 10 + o;                 // global mn channel (uniform)
        float a = 0.f;
#pragma unroll
        for (int i = 0; i < 8; ++i)
            a = fmaf(tv[i], w2[p * 80 + o * 8 + i], a);
        const float inv = g2[c] * rsqrtf(v2[c] + 1e-5f);
        const float add = be2[c] + (b2[c] - m2[c]) * inv;
        const float val = fmaf(a, inv, add);
        if (c < 8) {                              // neighbor plane
            nb[(size_t)(b * 8 + c) * HW + pix] = val;
        } else {                                  // mask plane [b][g][k]
            const int gk = c - 8, g = gk / 9, k = gk - 9 * g;
            mask[((size_t)(b * 8 + g) * 9 + k) * HW + pix] = val;
        }
    }
}

// ---- la_attn: softmax + tap-weighted x sum + Wv, all fp32, no v buffer.
//   out = rs * Wv . (sum_k e_k x_tap)   (Wv linear -> reorder past softmax)
//   x taps read directly from global: 8/9 of tap bytes are L1 line re-reads.
__global__ __launch_bounds__(256) void la_attn(
    const float* __restrict__ x, const float* __restrict__ wv,
    const float* __restrict__ nb, const float* __restrict__ mask,
    float* __restrict__ out)
{
    const int pix = blockIdx.x * blockDim.x + threadIdx.x;   // 0..16383
    const int y   = blockIdx.y;                              // 0..15
    const int b   = y >> 3, g = y & 7;
    const int iy  = pix >> 7, ix = pix & 127;

    const float* mp  = mask + ((size_t)(b * 8 + g) * 9) * HW + pix;
    const float* nbp = nb   + (size_t)(b * 8 + g) * HW + pix;
    const float* xg  = x    + (size_t)(b * 256 + g * 32) * HW + pix;

    // logits: mask at center + neighbor tap (zero-padded OOB, stays in softmax)
    float lg[9];
    float mx = -1e30f;
#pragma unroll
    for (int k = 0; k < 9; ++k) {
        const int dy = k / 3 - 1, dx = k % 3 - 1;
        const bool ok = ((unsigned)(iy + dy) < 128u) && ((unsigned)(ix + dx) < 128u);
        const float nv = ok ? nbp[dy * WD + dx] : 0.f;
        lg[k] = mp[(size_t)k * HW] + nv;
        mx = fmaxf(mx, lg[k]);
    }
    float ssum = 0.f;
#pragma unroll
    for (int k = 0; k < 9; ++k) { lg[k] = __expf(lg[k] - mx); ssum += lg[k]; }
    const float rs = 1.f / ssum;               // applied once at the store

    // s = sum_k e_k * x_tap  (fp32 from global; OOB taps contribute zero)
    float s[32];
#pragma unroll
    for (int c = 0; c < 32; ++c) s[c] = 0.f;
#pragma unroll
    for (int k = 0; k < 9; ++k) {
        const int dy = k / 3 - 1, dx = k % 3 - 1;
        const bool ok = ((unsigned)(iy + dy) < 128u) && ((unsigned)(ix + dx) < 128u);
        if (ok) {                                 // per-lane exec mask at edges
            const int off = dy * WD + dx;
            const float e = lg[k];
#pragma unroll
            for (int c = 0; c < 32; ++c)
                s[c] = fmaf(e, xg[(size_t)c * HW + off], s[c]);
        }
    }

    // out = rs * (Wv . s)   (weights thread-uniform -> scalar loads)
    const float* wvg = wv + g * 1024;
    float* og = out + (size_t)(b * 256 + g * 32) * HW + pix;
#pragma unroll 4
    for (int o = 0; o < 32; ++o) {
        const float* wp = wvg + o * 32;
        float a = 0.f;
#pragma unroll
        for (int ci = 0; ci < 32; ++ci) a = fmaf(s[ci], wp[ci], a);
        __builtin_nontemporal_store(a * rs, og + (size_t)o * HW);
    }
}

extern "C" void kernel_launch(void* const* d_in, const int* in_sizes, int n_in,
                              void* d_out, int out_size, void* d_ws, size_t ws_size,
                              hipStream_t stream)
{
    const float* x   = (const float*)d_in[0];
    const float* w1  = (const float*)d_in[1];
    const float* b1  = (const float*)d_in[2];
    const float* g1  = (const float*)d_in[3];
    const float* be1 = (const float*)d_in[4];
    const float* m1  = (const float*)d_in[5];
    const float* v1  = (const float*)d_in[6];
    const float* w2  = (const float*)d_in[7];
    const float* b2  = (const float*)d_in[8];
    const float* g2  = (const float*)d_in[9];
    const float* be2 = (const float*)d_in[10];
    const float* m2  = (const float*)d_in[11];
    const float* v2  = (const float*)d_in[12];
    const float* wv  = (const float*)d_in[13];

    float* out = (float*)d_out;

    // workspace: nb (fp32, 1 MB) | mask (fp32, 9.4 MB) — no v buffer
    float* nbw = (float*)d_ws;
    float* msk = nbw + (size_t)16 * HW;

    dim3 blk(256);
    dim3 gpre(HW / 256, 2, 16);    // 2048 blocks: px x b x (p*2+half)
    dim3 gatt(HW / 256, 16);       // 1024 blocks: px x (b,g)

    hipLaunchKernelGGL(la_pre, gpre, blk, 0, stream,
                       x, w1, b1, g1, be1, m1, v1, w2, b2, g2, be2, m2, v2,
                       nbw, msk);
    hipLaunchKernelGGL(la_attn, gatt, blk, 0, stream,
                       x, wv, nbw, msk, out);
}

// Round 7
// 126.794 us; speedup vs baseline: 1.1983x; 1.1983x over previous
//
#include <hip/hip_runtime.h>

#define HW  16384
#define WD  128

#define TS   16            // center tile side
#define HS   18            // halo side
#define HP   (HS * HS)     // 324 halo pixels
#define PRS  20            // padded halo row stride (slots)
#define PLS  360           // plane stride per c4 (ushort4 slots) = 18*20

__device__ __forceinline__ unsigned short f2bf(float f) {
    unsigned int u = __builtin_bit_cast(unsigned int, f);
    u += 0x7FFFu + ((u >> 16) & 1u);          // RNE
    return (unsigned short)(u >> 16);
}
__device__ __forceinline__ float bf2f(unsigned int s) {
    return __builtin_bit_cast(float, (s & 0xFFFFu) << 16);
}
__device__ __forceinline__ float ftanh(float v) {
    const float e = __expf(2.0f * v);
    return 1.0f - __fdividef(2.0f, e + 1.0f);
}

// ---- la_t: t = tanh(bn1(conv1(x))), channel-split 2x for TLP.
//   z = p*2 + h: this block computes conv1 outputs h*4..h*4+3 of group p,
//   stored as one dense ushort4 plane: t4[((b*8+p)*2+h)*HW + pix].
//   2048 blocks -> 32 waves/CU (vs 16 at R0/R3's 1024-block shape, which
//   measured 63.9us latency-bound, Occ 41%). x slab read by 2 sibling
//   blocks (2MB, L2/L3-shared). Plain launch_bounds: R4's (256,8) forced
//   VGPR=32 and spilled xv[32] to scratch — never bound min-waves here.
__global__ __launch_bounds__(256) void la_t(
    const float* __restrict__ x,
    const float* __restrict__ w1, const float* __restrict__ b1,
    const float* __restrict__ g1, const float* __restrict__ be1,
    const float* __restrict__ m1, const float* __restrict__ v1,
    ushort4* __restrict__ t4)
{
    const int pix = blockIdx.x * blockDim.x + threadIdx.x;   // 0..16383
    const int b   = blockIdx.y;
    const int z   = blockIdx.z;                              // 0..15
    const int p   = z >> 1;                                  // t-group
    const int h   = z & 1;                                   // output half

    const float* xp = x + (size_t)(b * 256 + p * 32) * HW + pix;
    float xv[32];
#pragma unroll
    for (int c = 0; c < 32; ++c) xv[c] = xp[(size_t)c * HW];

    const float* w1g = w1 + p * 256 + h * 4 * 32;
    float tv[4];
#pragma unroll
    for (int o = 0; o < 4; ++o) {
        float a = 0.f;
#pragma unroll
        for (int ci = 0; ci < 32; ++ci) a = fmaf(xv[ci], w1g[o * 32 + ci], a);
        const int ch = p * 8 + h * 4 + o;
        const float inv = g1[ch] * rsqrtf(v1[ch] + 1e-5f);
        const float add = be1[ch] + (b1[ch] - m1[ch]) * inv;
        tv[o] = ftanh(fmaf(a, inv, add));
    }

    t4[((size_t)((b * 8 + p) * 2 + h)) * HW + pix] =
        make_ushort4(f2bf(tv[0]), f2bf(tv[1]), f2bf(tv[2]), f2bf(tv[3]));
}

// ---- la_fused: x-tile copy (bf16 LDS) + in-block nb from t0 halo +
//                mask conv + softmax + out = Wv * (sum_k attn_k x_tap) ------
// grid = (16 bg, 64 tiles): linear id % 8 == g -> per-XCD x locality
__global__ __launch_bounds__(256, 4) void la_fused(
    const float* __restrict__ x,
    const float* __restrict__ w2, const float* __restrict__ b2,
    const float* __restrict__ g2, const float* __restrict__ be2,
    const float* __restrict__ m2, const float* __restrict__ v2,
    const float* __restrict__ wv,
    const ushort4* __restrict__ t4,
    float* __restrict__ out)
{
    __shared__ ushort4 xt[8 * PLS];            // x tile, bf16x4: 23040 B
    __shared__ float   nbs[PLS];               // neighbor plane fp32: 1440 B

    const int tid  = threadIdx.x;
    const int bg   = blockIdx.x;
    const int tile = blockIdx.y;               // 0..63
    const int b    = bg >> 3, g = bg & 7;
    const int ty0  = (tile >> 3) * TS;
    const int tx0  = (tile & 7) * TS;

    const float*   xg  = x  + (size_t)(b * 256 + g * 32) * HW;
    const ushort4* t0  = t4 + (size_t)(b * 16) * HW;      // group-0 planes h=0,1

    // bn2 constants for neighbor channel g (conv2 group 0, out row g)
    const float inv2n = g2[g] * rsqrtf(v2[g] + 1e-5f);
    const float add2n = be2[g] + (b2[g] - m2[g]) * inv2n;

    // ---- phase 1: halo -> bf16 LDS x tile + nb plane from t0 ----
    for (int hp = tid; hp < HP; hp += 256) {
        const int hy = hp / HS, hx = hp - hy * HS;
        const int iy = ty0 + hy - 1, ix = tx0 + hx - 1;
        const int slot = hy * PRS + hx;
        if (((unsigned)iy < 128u) && ((unsigned)ix < 128u)) {
            const int po = iy * WD + ix;
            float xv[32];
#pragma unroll
            for (int c = 0; c < 32; ++c) xv[c] = xg[(size_t)c * HW + po];
            // nb = bn2(conv2 row g of group 0, applied to bf16 t0)
            const ushort4 ta = t0[po];
            const ushort4 tb = t0[(size_t)HW + po];
            float an = 0.f;
            an = fmaf(bf2f(ta.x), w2[g * 8 + 0], an);
            an = fmaf(bf2f(ta.y), w2[g * 8 + 1], an);
            an = fmaf(bf2f(ta.z), w2[g * 8 + 2], an);
            an = fmaf(bf2f(ta.w), w2[g * 8 + 3], an);
            an = fmaf(bf2f(tb.x), w2[g * 8 + 4], an);
            an = fmaf(bf2f(tb.y), w2[g * 8 + 5], an);
            an = fmaf(bf2f(tb.z), w2[g * 8 + 6], an);
            an = fmaf(bf2f(tb.w), w2[g * 8 + 7], an);
            nbs[slot] = fmaf(an, inv2n, add2n);
#pragma unroll
            for (int c4 = 0; c4 < 8; ++c4)
                xt[c4 * PLS + slot] = make_ushort4(
                    f2bf(xv[c4 * 4 + 0]), f2bf(xv[c4 * 4 + 1]),
                    f2bf(xv[c4 * 4 + 2]), f2bf(xv[c4 * 4 + 3]));
        } else {
            const ushort4 z = make_ushort4(0, 0, 0, 0);
#pragma unroll
            for (int c4 = 0; c4 < 8; ++c4) xt[c4 * PLS + slot] = z;
            nbs[slot] = 0.f;       // zero-padded neighbor
        }
    }
    __syncthreads();

    // ---- phase 2: one center pixel per thread ----
    const int cy  = tid >> 4, cx = tid & 15;
    const int iy  = ty0 + cy, ix = tx0 + cx;
    const int pix = iy * WD + ix;

    // mask channels mc0..mc0+8 produced by t-groups pa (k<ksplit) and pb
    const int mc0    = 8 + 9 * g;
    const int pa     = mc0 / 10;               // == g
    const int pb     = (mc0 + 8) / 10;         // == min(g+1, 7)
    const int ksplit = 10 - (mc0 - pa * 10);

    float tA[8], tB[8];
    {
        const ushort4 lo = t4[((size_t)((b * 8 + pa) * 2 + 0)) * HW + pix];
        const ushort4 hi = t4[((size_t)((b * 8 + pa) * 2 + 1)) * HW + pix];
        tA[0] = bf2f(lo.x); tA[1] = bf2f(lo.y);
        tA[2] = bf2f(lo.z); tA[3] = bf2f(lo.w);
        tA[4] = bf2f(hi.x); tA[5] = bf2f(hi.y);
        tA[6] = bf2f(hi.z); tA[7] = bf2f(hi.w);
    }
    if (pb != pa) {
        const ushort4 lo = t4[((size_t)((b * 8 + pb) * 2 + 0)) * HW + pix];
        const ushort4 hi = t4[((size_t)((b * 8 + pb) * 2 + 1)) * HW + pix];
        tB[0] = bf2f(lo.x); tB[1] = bf2f(lo.y);
        tB[2] = bf2f(lo.z); tB[3] = bf2f(lo.w);
        tB[4] = bf2f(hi.x); tB[5] = bf2f(hi.y);
        tB[6] = bf2f(hi.z); tB[7] = bf2f(hi.w);
    } else {
#pragma unroll
        for (int o = 0; o < 8; ++o) tB[o] = tA[o];
    }

    float lg[9];
    float mx = -1e30f;
#pragma unroll
    for (int k = 0; k < 9; ++k) {
        const int mc = mc0 + k;
        const int p  = (k < ksplit) ? pa : pb;
        const int o  = mc - p * 10;
        const float* w2p = w2 + p * 80 + o * 8;
        float a = 0.f;
#pragma unroll
        for (int i = 0; i < 8; ++i) {
            const float ti = (k < ksplit) ? tA[i] : tB[i];
            a = fmaf(ti, w2p[i], a);
        }
        const float inv = g2[mc] * rsqrtf(v2[mc] + 1e-5f);
        const float add = be2[mc] + (b2[mc] - m2[mc]) * inv;
        lg[k] = fmaf(a, inv, add) + nbs[(cy + k / 3) * PRS + (cx + k % 3)];
        mx = fmaxf(mx, lg[k]);
    }
    float ssum = 0.f;
#pragma unroll
    for (int k = 0; k < 9; ++k) { lg[k] = __expf(lg[k] - mx); ssum += lg[k]; }
    const float rs = 1.f / ssum;               // applied once at the store

    // s = sum_k e_k * x_tap  (OOB taps read x==0 from LDS)
    float s[32];
#pragma unroll
    for (int c = 0; c < 32; ++c) s[c] = 0.f;
#pragma unroll
    for (int k = 0; k < 9; ++k) {
        const int slot = (cy + k / 3) * PRS + (cx + k % 3);
        const float e = lg[k];
#pragma unroll
        for (int c4 = 0; c4 < 8; ++c4) {
            const ushort4 xv4 = xt[c4 * PLS + slot];
            s[c4 * 4 + 0] = fmaf(e, bf2f(xv4.x), s[c4 * 4 + 0]);
            s[c4 * 4 + 1] = fmaf(e, bf2f(xv4.y), s[c4 * 4 + 1]);
            s[c4 * 4 + 2] = fmaf(e, bf2f(xv4.z), s[c4 * 4 + 2]);
            s[c4 * 4 + 3] = fmaf(e, bf2f(xv4.w), s[c4 * 4 + 3]);
        }
    }

    // out = rs * (Wv . s)
    const float* wvg = wv + g * 1024;
    float* og = out + (size_t)(b * 256 + g * 32) * HW + pix;
#pragma unroll 4
    for (int o = 0; o < 32; ++o) {
        const float* wp = wvg + o * 32;
        float a = 0.f;
#pragma unroll
        for (int ci = 0; ci < 32; ++ci) a = fmaf(s[ci], wp[ci], a);
        __builtin_nontemporal_store(a * rs, og + (size_t)o * HW);
    }
}

extern "C" void kernel_launch(void* const* d_in, const int* in_sizes, int n_in,
                              void* d_out, int out_size, void* d_ws, size_t ws_size,
                              hipStream_t stream)
{
    const float* x   = (const float*)d_in[0];
    const float* w1  = (const float*)d_in[1];
    const float* b1  = (const float*)d_in[2];
    const float* g1  = (const float*)d_in[3];
    const float* be1 = (const float*)d_in[4];
    const float* m1  = (const float*)d_in[5];
    const float* v1  = (const float*)d_in[6];
    const float* w2  = (const float*)d_in[7];
    const float* b2  = (const float*)d_in[8];
    const float* g2  = (const float*)d_in[9];
    const float* be2 = (const float*)d_in[10];
    const float* m2  = (const float*)d_in[11];
    const float* v2  = (const float*)d_in[12];
    const float* wv  = (const float*)d_in[13];

    float* out = (float*)d_out;
    ushort4* t4 = (ushort4*)d_ws;      // 32 dense planes x 16384 x 8B = 4.2 MB

    dim3 blk(256);
    dim3 gt(HW / 256, 2, 16);      // 2048 blocks: px x b x (p*2+h)
    dim3 grd(16, 64);              // (bg, tile): id%8==g -> XCD locality

    hipLaunchKernelGGL(la_t, gt, blk, 0, stream,
                       x, w1, b1, g1, be1, m1, v1, t4);
    hipLaunchKernelGGL(la_fused, grd, blk, 0, stream,
                       x, w2, b2, g2, be2, m2, v2, wv, t4, out);
}